// Round 1
// baseline (8928.498 us; speedup 1.0000x reference)
//
#include <hip/hip_runtime.h>

#define NN 20000
#define EE 320000

__device__ __forceinline__ float silu_f(float x) {
    return x / (1.0f + __expf(-x));
}

// ---------------- Kernel 1: node up-projection ----------------
// up[n][0:64]          = (s @ W_up_s) / 8
// up[n][64 + k*3 + c]  = (sum_m v[m][c] * W_up_v[m][k]) / 8
__global__ __launch_bounds__(256) void up_kernel(
    const float* __restrict__ nf, const float* __restrict__ Wus,
    const float* __restrict__ Wuv, float* __restrict__ up)
{
    __shared__ float sWs[64 * 64];
    __shared__ float sWv[64 * 64];
    int tid = threadIdx.x;
    for (int i = tid; i < 64 * 64; i += 256) { sWs[i] = Wus[i]; sWv[i] = Wuv[i]; }
    __syncthreads();
    int lane = tid & 63, wv = tid >> 6;
    int n = blockIdx.x * 4 + wv;
    if (n >= NN) return;
    const float* row = nf + (size_t)n * 256;
    float s  = row[lane];
    float v0 = row[64 + lane * 3 + 0];
    float v1 = row[64 + lane * 3 + 1];
    float v2 = row[64 + lane * 3 + 2];
    float as = 0.f, a0 = 0.f, a1 = 0.f, a2 = 0.f;
    #pragma unroll 8
    for (int m = 0; m < 64; m++) {
        float sm = __shfl(s, m);
        float b0 = __shfl(v0, m), b1 = __shfl(v1, m), b2 = __shfl(v2, m);
        float w_s = sWs[m * 64 + lane];
        float w_v = sWv[m * 64 + lane];
        as += sm * w_s;
        a0 += b0 * w_v; a1 += b1 * w_v; a2 += b2 * w_v;
    }
    float* o = up + (size_t)n * 256;
    o[lane] = as * 0.125f;
    o[64 + lane * 3 + 0] = a0 * 0.125f;
    o[64 + lane * 3 + 1] = a1 * 0.125f;
    o[64 + lane * 3 + 2] = a2 * 0.125f;
}

// ---------------- Kernel 2: fused edge MLP + messages + atomic scatter ----------------
// thread-per-edge; hidden layers live in per-thread LDS columns hX[k*256 + tid]
// (lane-consecutive => bank-conflict-free). Weight indices are wave-uniform =>
// compiler emits scalar s_load, FMAs take SGPR operand.
__global__ __launch_bounds__(256) void edge_kernel(
    const float* __restrict__ vectors, const float* __restrict__ radial,
    const int* __restrict__ senders, const int* __restrict__ receivers,
    const float* __restrict__ w1, const float* __restrict__ w2,
    const float* __restrict__ w3, const float* __restrict__ wo,
    const float* __restrict__ up, float* __restrict__ agg)
{
    __shared__ float hA[64 * 256];   // 64 KiB
    __shared__ float hB[64 * 256];   // 64 KiB  (128 KiB total -> 1 block/CU)
    int tid = threadIdx.x;
    int e = blockIdx.x * 256 + tid;
    bool valid = (e < EE);
    int snd = 0, rcv = 0;
    float r[8];
    if (valid) {
        snd = senders[e];
        rcv = receivers[e];
        #pragma unroll
        for (int i = 0; i < 8; i++) r[i] = radial[(size_t)e * 8 + i];
    } else {
        #pragma unroll
        for (int i = 0; i < 8; i++) r[i] = 0.f;
    }

    // layer 1: 8 -> 64
    for (int j = 0; j < 64; j++) {
        float acc = 0.f;
        #pragma unroll
        for (int i = 0; i < 8; i++) acc += r[i] * w1[i * 64 + j];
        hA[j * 256 + tid] = silu_f(acc * 0.35355339059327373f);
    }
    // layer 2: 64 -> 64  (hA -> hB)
    for (int jb = 0; jb < 8; jb++) {
        float acc[8] = {0.f, 0.f, 0.f, 0.f, 0.f, 0.f, 0.f, 0.f};
        #pragma unroll 8
        for (int k = 0; k < 64; k++) {
            float hk = hA[k * 256 + tid];
            #pragma unroll
            for (int c = 0; c < 8; c++) acc[c] += hk * w2[k * 64 + jb * 8 + c];
        }
        #pragma unroll
        for (int c = 0; c < 8; c++) hB[(jb * 8 + c) * 256 + tid] = silu_f(acc[c] * 0.125f);
    }
    // layer 3: 64 -> 64  (hB -> hA)
    for (int jb = 0; jb < 8; jb++) {
        float acc[8] = {0.f, 0.f, 0.f, 0.f, 0.f, 0.f, 0.f, 0.f};
        #pragma unroll 8
        for (int k = 0; k < 64; k++) {
            float hk = hB[k * 256 + tid];
            #pragma unroll
            for (int c = 0; c < 8; c++) acc[c] += hk * w3[k * 64 + jb * 8 + c];
        }
        #pragma unroll
        for (int c = 0; c < 8; c++) hA[(jb * 8 + c) * 256 + tid] = silu_f(acc[c] * 0.125f);
    }

    // geometry
    float vx = 0.f, vy = 0.f, vz = 0.f;
    if (valid) {
        vx = vectors[(size_t)e * 3 + 0];
        vy = vectors[(size_t)e * 3 + 1];
        vz = vectors[(size_t)e * 3 + 2];
    }
    float len = sqrtf(vx * vx + vy * vy + vz * vz);
    float invlen = (len > 0.f) ? (1.f / len) : 0.f;
    float mask   = (len > 0.f) ? 1.f : 0.f;
    const float SQ3 = 1.7320508075688772f;
    float yx = SQ3 * vx * invlen, yy = SQ3 * vy * invlen, yz = SQ3 * vz * invlen;
    const float* uprow = up + (size_t)snd * 256;
    float* aggrow = agg + (size_t)rcv * 512;

    // output layer: 64 -> 256, fused with message formation + atomic scatter
    for (int jb = 0; jb < 32; jb++) {
        float acc[8] = {0.f, 0.f, 0.f, 0.f, 0.f, 0.f, 0.f, 0.f};
        #pragma unroll 8
        for (int k = 0; k < 64; k++) {
            float hk = hA[k * 256 + tid];
            #pragma unroll
            for (int c = 0; c < 8; c++) acc[c] += hk * wo[k * 256 + jb * 8 + c];
        }
        if (!valid) continue;
        int grp  = jb >> 3;          // which 64-block of mix
        int base = (jb & 7) * 8;     // offset within block
        if (grp == 0) {
            // msg_s[m] = es[m] * mix[m]
            #pragma unroll
            for (int c = 0; c < 8; c++) {
                int m = base + c;
                float mix = acc[c] * 0.125f * mask;
                atomicAdd(aggrow + m, uprow[m] * mix);
            }
        } else if (grp == 1) {
            // msg_s[64+m] = tp_s[m] * mix[64+m],  tp_s[m] = (ev[m] . vec) / len
            #pragma unroll
            for (int c = 0; c < 8; c++) {
                int m = base + c;
                float mix = acc[c] * 0.125f * mask;
                float e0 = uprow[64 + m * 3 + 0];
                float e1 = uprow[64 + m * 3 + 1];
                float e2 = uprow[64 + m * 3 + 2];
                float tps = (e0 * vx + e1 * vy + e2 * vz) * invlen;
                atomicAdd(aggrow + 64 + m, tps * mix);
            }
        } else if (grp == 2) {
            // msg_v[m][c2] = ev[m][c2] * mix[128+m]
            #pragma unroll
            for (int c = 0; c < 8; c++) {
                int m = base + c;
                float mix = acc[c] * 0.125f * mask;
                float e0 = uprow[64 + m * 3 + 0];
                float e1 = uprow[64 + m * 3 + 1];
                float e2 = uprow[64 + m * 3 + 2];
                atomicAdd(aggrow + 128 + m * 3 + 0, e0 * mix);
                atomicAdd(aggrow + 128 + m * 3 + 1, e1 * mix);
                atomicAdd(aggrow + 128 + m * 3 + 2, e2 * mix);
            }
        } else {
            // msg_v[64+m][c2] = es[m] * y[c2] * mix[192+m]
            #pragma unroll
            for (int c = 0; c < 8; c++) {
                int m = base + c;
                float mix = acc[c] * 0.125f * mask;
                float es = uprow[m];
                atomicAdd(aggrow + 320 + m * 3 + 0, es * yx * mix);
                atomicAdd(aggrow + 320 + m * 3 + 1, es * yy * mix);
                atomicAdd(aggrow + 320 + m * 3 + 2, es * yz * mix);
            }
        }
    }
}

// ---------------- Kernel 3: node tail (down + skip + gate + relu) ----------------
__global__ __launch_bounds__(256) void node_kernel(
    const float* __restrict__ nf, const int* __restrict__ specie,
    const float* __restrict__ Wds, const float* __restrict__ Wdv,
    const float* __restrict__ Wss, const float* __restrict__ Wsv,
    const float* __restrict__ agg, float* __restrict__ out)
{
    __shared__ float sDs[128 * 128];  // 64 KiB
    __shared__ float sDv[128 * 64];   // 32 KiB
    int tid = threadIdx.x;
    for (int i = tid; i < 128 * 128; i += 256) sDs[i] = Wds[i];
    for (int i = tid; i < 128 * 64; i += 256) sDv[i] = Wdv[i];
    __syncthreads();
    int lane = tid & 63, wv = tid >> 6;
    int n = blockIdx.x * 4 + wv;
    if (n >= NN) return;
    const float* arow = agg + (size_t)n * 512;
    const float inv_nei = 0.25f;  // 1/sqrt(16)
    float as0 = arow[lane] * inv_nei;
    float as1 = arow[64 + lane] * inv_nei;
    float av00 = arow[128 + lane * 3 + 0] * inv_nei;
    float av01 = arow[128 + lane * 3 + 1] * inv_nei;
    float av02 = arow[128 + lane * 3 + 2] * inv_nei;
    float av10 = arow[320 + lane * 3 + 0] * inv_nei;
    float av11 = arow[320 + lane * 3 + 1] * inv_nei;
    float av12 = arow[320 + lane * 3 + 2] * inv_nei;
    const float* row = nf + (size_t)n * 256;
    float s   = row[lane];
    float vv0 = row[64 + lane * 3 + 0];
    float vv1 = row[64 + lane * 3 + 1];
    float vv2 = row[64 + lane * 3 + 2];

    float f0 = 0.f, f1 = 0.f, fv0 = 0.f, fv1 = 0.f, fv2 = 0.f;
    #pragma unroll 8
    for (int m = 0; m < 64; m++) {
        float am = __shfl(as0, m);
        f0 += am * sDs[m * 128 + lane];
        f1 += am * sDs[m * 128 + 64 + lane];
        float b0 = __shfl(av00, m), b1 = __shfl(av01, m), b2 = __shfl(av02, m);
        float wd = sDv[m * 64 + lane];
        fv0 += b0 * wd; fv1 += b1 * wd; fv2 += b2 * wd;
    }
    #pragma unroll 8
    for (int m = 0; m < 64; m++) {
        float am = __shfl(as1, m);
        f0 += am * sDs[(64 + m) * 128 + lane];
        f1 += am * sDs[(64 + m) * 128 + 64 + lane];
        float b0 = __shfl(av10, m), b1 = __shfl(av11, m), b2 = __shfl(av12, m);
        float wd = sDv[(64 + m) * 64 + lane];
        fv0 += b0 * wd; fv1 += b1 * wd; fv2 += b2 * wd;
    }
    const float inv2m = 0.08838834764831845f;  // 1/sqrt(128)
    f0 *= inv2m; f1 *= inv2m; fv0 *= inv2m; fv1 *= inv2m; fv2 *= inv2m;

    int sp = specie[n];
    const float* Ws = Wss + (size_t)sp * 64 * 128;
    const float* Wv = Wsv + (size_t)sp * 64 * 64;
    float g0 = 0.f, g1 = 0.f, h0 = 0.f, h1 = 0.f, h2 = 0.f;
    #pragma unroll 4
    for (int m = 0; m < 64; m++) {
        float sm = __shfl(s, m);
        g0 += sm * Ws[m * 128 + lane];
        g1 += sm * Ws[m * 128 + 64 + lane];
        float b0 = __shfl(vv0, m), b1 = __shfl(vv1, m), b2 = __shfl(vv2, m);
        float wsk = Wv[m * 64 + lane];
        h0 += b0 * wsk; h1 += b1 * wsk; h2 += b2 * wsk;
    }
    f0 += g0 * 0.125f; f1 += g1 * 0.125f;
    fv0 += h0 * 0.125f; fv1 += h1 * 0.125f; fv2 += h2 * 0.125f;

    float gs   = silu_f(f0);
    float gate = silu_f(f1);
    float* orow = out + (size_t)n * 256;
    orow[lane] = fmaxf(gs, 0.f);
    orow[64 + lane * 3 + 0] = fmaxf(gate * fv0, 0.f);
    orow[64 + lane * 3 + 1] = fmaxf(gate * fv1, 0.f);
    orow[64 + lane * 3 + 2] = fmaxf(gate * fv2, 0.f);
}

extern "C" void kernel_launch(void* const* d_in, const int* in_sizes, int n_in,
                              void* d_out, int out_size, void* d_ws, size_t ws_size,
                              hipStream_t stream) {
    const float* vectors     = (const float*)d_in[0];
    const float* node_feats  = (const float*)d_in[1];
    const int*   node_specie = (const int*)d_in[2];
    const float* radial      = (const float*)d_in[3];
    const int*   senders     = (const int*)d_in[4];
    const int*   receivers   = (const int*)d_in[5];
    const float* W_up_s      = (const float*)d_in[6];
    const float* W_up_v      = (const float*)d_in[7];
    const float* mlp_w1      = (const float*)d_in[8];
    const float* mlp_w2      = (const float*)d_in[9];
    const float* mlp_w3      = (const float*)d_in[10];
    const float* mlp_wo      = (const float*)d_in[11];
    const float* W_skip_s    = (const float*)d_in[12];
    const float* W_skip_v    = (const float*)d_in[13];
    const float* W_down_s    = (const float*)d_in[14];
    const float* W_down_v    = (const float*)d_in[15];
    float* out = (float*)d_out;

    float* up  = (float*)d_ws;                  // N*256 floats = 20.48 MB
    float* agg = up + (size_t)NN * 256;         // N*512 floats = 40.96 MB

    hipMemsetAsync(agg, 0, (size_t)NN * 512 * sizeof(float), stream);
    up_kernel<<<(NN + 3) / 4, 256, 0, stream>>>(node_feats, W_up_s, W_up_v, up);
    edge_kernel<<<(EE + 255) / 256, 256, 0, stream>>>(
        vectors, radial, senders, receivers,
        mlp_w1, mlp_w2, mlp_w3, mlp_wo, up, agg);
    node_kernel<<<(NN + 3) / 4, 256, 0, stream>>>(
        node_feats, node_specie, W_down_s, W_down_v, W_skip_s, W_skip_v, agg, out);
}

// Round 2
// 2020.136 us; speedup vs baseline: 4.4198x; 4.4198x over previous
//
#include <hip/hip_runtime.h>

#define NN 20000
#define EE 320000

__device__ __forceinline__ float silu_f(float x) {
    return x / (1.0f + __expf(-x));
}

// ---------------- Kernel 1: node up-projection ----------------
__global__ __launch_bounds__(256) void up_kernel(
    const float* __restrict__ nf, const float* __restrict__ Wus,
    const float* __restrict__ Wuv, float* __restrict__ up)
{
    __shared__ float sWs[64 * 64];
    __shared__ float sWv[64 * 64];
    int tid = threadIdx.x;
    for (int i = tid; i < 64 * 64; i += 256) { sWs[i] = Wus[i]; sWv[i] = Wuv[i]; }
    __syncthreads();
    int lane = tid & 63, wv = tid >> 6;
    int n = blockIdx.x * 4 + wv;
    if (n >= NN) return;
    const float* row = nf + (size_t)n * 256;
    float s  = row[lane];
    float v0 = row[64 + lane * 3 + 0];
    float v1 = row[64 + lane * 3 + 1];
    float v2 = row[64 + lane * 3 + 2];
    float as = 0.f, a0 = 0.f, a1 = 0.f, a2 = 0.f;
    #pragma unroll 8
    for (int m = 0; m < 64; m++) {
        float sm = __shfl(s, m);
        float b0 = __shfl(v0, m), b1 = __shfl(v1, m), b2 = __shfl(v2, m);
        float w_s = sWs[m * 64 + lane];
        float w_v = sWv[m * 64 + lane];
        as += sm * w_s;
        a0 += b0 * w_v; a1 += b1 * w_v; a2 += b2 * w_v;
    }
    float* o = up + (size_t)n * 256;
    o[lane] = as * 0.125f;
    o[64 + lane * 3 + 0] = a0 * 0.125f;
    o[64 + lane * 3 + 1] = a1 * 0.125f;
    o[64 + lane * 3 + 2] = a2 * 0.125f;
}

// ---------------- Kernel 2: fused edge MLP + wave-coalesced atomic scatter ----------------
// MLP: thread-per-edge, hidden activations in LDS columns h[k*256+tid] (lane-contiguous,
// conflict-free), weights wave-uniform (scalar loads).
// Scatter: mix computed in 4 chunks of 64; each chunk transposed through XOR-swizzled
// LDS, then the wave walks its own 64 edges issuing CONTIGUOUS 256B atomic spans
// into the receiver's agg row (8 atomic wave-instrs/edge, 4 lines each vs 64 before).
__global__ __launch_bounds__(256) void edge_kernel(
    const float* __restrict__ vectors, const float* __restrict__ radial,
    const int* __restrict__ senders, const int* __restrict__ receivers,
    const float* __restrict__ w1, const float* __restrict__ w2,
    const float* __restrict__ w3, const float* __restrict__ wo,
    const float* __restrict__ up, float* __restrict__ agg)
{
    __shared__ float hA[64 * 256];   // 64 KiB
    __shared__ float hB[64 * 256];   // 64 KiB
    __shared__ int   sSnd[256];
    __shared__ int   sRcv[256];
    __shared__ float4 sGeo[256];     // vx, vy, vz, invlen   (total ~134 KiB)

    int tid = threadIdx.x;
    int e = blockIdx.x * 256 + tid;
    bool valid = (e < EE);
    int snd = 0, rcv = 0;
    float r[8];
    if (valid) {
        snd = senders[e];
        rcv = receivers[e];
        float4 ra = *(const float4*)(radial + (size_t)e * 8);
        float4 rb = *(const float4*)(radial + (size_t)e * 8 + 4);
        r[0] = ra.x; r[1] = ra.y; r[2] = ra.z; r[3] = ra.w;
        r[4] = rb.x; r[5] = rb.y; r[6] = rb.z; r[7] = rb.w;
    } else {
        #pragma unroll
        for (int i = 0; i < 8; i++) r[i] = 0.f;
    }

    // geometry
    float vx = 0.f, vy = 0.f, vz = 0.f;
    if (valid) {
        vx = vectors[(size_t)e * 3 + 0];
        vy = vectors[(size_t)e * 3 + 1];
        vz = vectors[(size_t)e * 3 + 2];
    }
    float len = sqrtf(vx * vx + vy * vy + vz * vz);
    float invlen = (len > 0.f) ? (1.f / len) : 0.f;
    float mask   = (len > 0.f) ? 1.f : 0.f;
    sSnd[tid] = snd;
    sRcv[tid] = rcv;
    sGeo[tid] = make_float4(vx, vy, vz, invlen);

    // layer 1: 8 -> 64
    for (int j = 0; j < 64; j++) {
        float acc = 0.f;
        #pragma unroll
        for (int i = 0; i < 8; i++) acc += r[i] * w1[i * 64 + j];
        hA[j * 256 + tid] = silu_f(acc * 0.35355339059327373f);
    }
    // layer 2: 64 -> 64  (hA -> hB)
    for (int jb = 0; jb < 8; jb++) {
        float acc[8] = {0.f, 0.f, 0.f, 0.f, 0.f, 0.f, 0.f, 0.f};
        #pragma unroll 8
        for (int k = 0; k < 64; k++) {
            float hk = hA[k * 256 + tid];
            #pragma unroll
            for (int c = 0; c < 8; c++) acc[c] += hk * w2[k * 64 + jb * 8 + c];
        }
        #pragma unroll
        for (int c = 0; c < 8; c++) hB[(jb * 8 + c) * 256 + tid] = silu_f(acc[c] * 0.125f);
    }
    // layer 3: 64 -> 64  (hB -> hA)
    for (int jb = 0; jb < 8; jb++) {
        float acc[8] = {0.f, 0.f, 0.f, 0.f, 0.f, 0.f, 0.f, 0.f};
        #pragma unroll 8
        for (int k = 0; k < 64; k++) {
            float hk = hB[k * 256 + tid];
            #pragma unroll
            for (int c = 0; c < 8; c++) acc[c] += hk * w3[k * 64 + jb * 8 + c];
        }
        #pragma unroll
        for (int c = 0; c < 8; c++) hA[(jb * 8 + c) * 256 + tid] = silu_f(acc[c] * 0.125f);
    }

    int lane  = tid & 63;
    int wbase = tid & ~63;          // wave's first column
    const float SQ3 = 1.7320508075688772f;

    // output layer in 4 chunks of 64 (mix[q*64 .. q*64+63]) + transposed scatter
    for (int q = 0; q < 4; q++) {
        // ---- compute chunk q into swizzled hB: hB[jl*256 + (tid ^ (jl&31))] ----
        for (int jb = 0; jb < 8; jb++) {
            float acc[8] = {0.f, 0.f, 0.f, 0.f, 0.f, 0.f, 0.f, 0.f};
            #pragma unroll 8
            for (int k = 0; k < 64; k++) {
                float hk = hA[k * 256 + tid];
                #pragma unroll
                for (int c = 0; c < 8; c++) acc[c] += hk * wo[k * 256 + q * 64 + jb * 8 + c];
            }
            #pragma unroll
            for (int c = 0; c < 8; c++) {
                int jl = jb * 8 + c;
                hB[jl * 256 + (tid ^ (jl & 31))] = acc[c] * 0.125f * mask;
            }
        }
        // ---- wave-coalesced scatter of this chunk over the wave's 64 edges ----
        for (int el = 0; el < 64; el++) {
            int col = wbase + el;
            int ecol = blockIdx.x * 256 + col;
            if (ecol >= EE) break;                 // wave-uniform
            int    s_ = sSnd[col];                 // same-address broadcast reads
            int    rc = sRcv[col];
            const float* uprow = up + (size_t)s_ * 256;
            float* aggrow = agg + (size_t)rc * 512;
            if (q == 0) {
                float mx = hB[lane * 256 + (col ^ (lane & 31))];
                atomicAdd(aggrow + lane, uprow[lane] * mx);
            } else if (q == 1) {
                float4 g = sGeo[col];
                float mx = hB[lane * 256 + (col ^ (lane & 31))];
                float e0 = uprow[64 + lane * 3 + 0];
                float e1 = uprow[64 + lane * 3 + 1];
                float e2 = uprow[64 + lane * 3 + 2];
                float tps = (e0 * g.x + e1 * g.y + e2 * g.z) * g.w;
                atomicAdd(aggrow + 64 + lane, tps * mx);
            } else if (q == 2) {
                #pragma unroll
                for (int i = 0; i < 3; i++) {
                    int x = i * 64 + lane;               // 0..191
                    int m = (x * 21846) >> 16;           // x / 3
                    float mx = hB[m * 256 + (col ^ (m & 31))];
                    atomicAdd(aggrow + 128 + x, uprow[64 + x] * mx);
                }
            } else {
                float4 g = sGeo[col];
                float yx = SQ3 * g.x * g.w, yy = SQ3 * g.y * g.w, yz = SQ3 * g.z * g.w;
                #pragma unroll
                for (int i = 0; i < 3; i++) {
                    int x = i * 64 + lane;
                    int m = (x * 21846) >> 16;
                    int c = x - 3 * m;
                    float mx = hB[m * 256 + (col ^ (m & 31))];
                    float esm = uprow[m];
                    float yc = (c == 0) ? yx : ((c == 1) ? yy : yz);
                    atomicAdd(aggrow + 320 + x, esm * yc * mx);
                }
            }
        }
    }
}

// ---------------- Kernel 3: node tail (down + skip + gate + relu) ----------------
__global__ __launch_bounds__(256) void node_kernel(
    const float* __restrict__ nf, const int* __restrict__ specie,
    const float* __restrict__ Wds, const float* __restrict__ Wdv,
    const float* __restrict__ Wss, const float* __restrict__ Wsv,
    const float* __restrict__ agg, float* __restrict__ out)
{
    __shared__ float sDs[128 * 128];  // 64 KiB
    __shared__ float sDv[128 * 64];   // 32 KiB
    int tid = threadIdx.x;
    for (int i = tid; i < 128 * 128; i += 256) sDs[i] = Wds[i];
    for (int i = tid; i < 128 * 64; i += 256) sDv[i] = Wdv[i];
    __syncthreads();
    int lane = tid & 63, wv = tid >> 6;
    int n = blockIdx.x * 4 + wv;
    if (n >= NN) return;
    const float* arow = agg + (size_t)n * 512;
    const float inv_nei = 0.25f;  // 1/sqrt(16)
    float as0 = arow[lane] * inv_nei;
    float as1 = arow[64 + lane] * inv_nei;
    float av00 = arow[128 + lane * 3 + 0] * inv_nei;
    float av01 = arow[128 + lane * 3 + 1] * inv_nei;
    float av02 = arow[128 + lane * 3 + 2] * inv_nei;
    float av10 = arow[320 + lane * 3 + 0] * inv_nei;
    float av11 = arow[320 + lane * 3 + 1] * inv_nei;
    float av12 = arow[320 + lane * 3 + 2] * inv_nei;
    const float* row = nf + (size_t)n * 256;
    float s   = row[lane];
    float vv0 = row[64 + lane * 3 + 0];
    float vv1 = row[64 + lane * 3 + 1];
    float vv2 = row[64 + lane * 3 + 2];

    float f0 = 0.f, f1 = 0.f, fv0 = 0.f, fv1 = 0.f, fv2 = 0.f;
    #pragma unroll 8
    for (int m = 0; m < 64; m++) {
        float am = __shfl(as0, m);
        f0 += am * sDs[m * 128 + lane];
        f1 += am * sDs[m * 128 + 64 + lane];
        float b0 = __shfl(av00, m), b1 = __shfl(av01, m), b2 = __shfl(av02, m);
        float wd = sDv[m * 64 + lane];
        fv0 += b0 * wd; fv1 += b1 * wd; fv2 += b2 * wd;
    }
    #pragma unroll 8
    for (int m = 0; m < 64; m++) {
        float am = __shfl(as1, m);
        f0 += am * sDs[(64 + m) * 128 + lane];
        f1 += am * sDs[(64 + m) * 128 + 64 + lane];
        float b0 = __shfl(av10, m), b1 = __shfl(av11, m), b2 = __shfl(av12, m);
        float wd = sDv[(64 + m) * 64 + lane];
        fv0 += b0 * wd; fv1 += b1 * wd; fv2 += b2 * wd;
    }
    const float inv2m = 0.08838834764831845f;  // 1/sqrt(128)
    f0 *= inv2m; f1 *= inv2m; fv0 *= inv2m; fv1 *= inv2m; fv2 *= inv2m;

    int sp = specie[n];
    const float* Ws = Wss + (size_t)sp * 64 * 128;
    const float* Wv = Wsv + (size_t)sp * 64 * 64;
    float g0 = 0.f, g1 = 0.f, h0 = 0.f, h1 = 0.f, h2 = 0.f;
    #pragma unroll 4
    for (int m = 0; m < 64; m++) {
        float sm = __shfl(s, m);
        g0 += sm * Ws[m * 128 + lane];
        g1 += sm * Ws[m * 128 + 64 + lane];
        float b0 = __shfl(vv0, m), b1 = __shfl(vv1, m), b2 = __shfl(vv2, m);
        float wsk = Wv[m * 64 + lane];
        h0 += b0 * wsk; h1 += b1 * wsk; h2 += b2 * wsk;
    }
    f0 += g0 * 0.125f; f1 += g1 * 0.125f;
    fv0 += h0 * 0.125f; fv1 += h1 * 0.125f; fv2 += h2 * 0.125f;

    float gs   = silu_f(f0);
    float gate = silu_f(f1);
    float* orow = out + (size_t)n * 256;
    orow[lane] = fmaxf(gs, 0.f);
    orow[64 + lane * 3 + 0] = fmaxf(gate * fv0, 0.f);
    orow[64 + lane * 3 + 1] = fmaxf(gate * fv1, 0.f);
    orow[64 + lane * 3 + 2] = fmaxf(gate * fv2, 0.f);
}

extern "C" void kernel_launch(void* const* d_in, const int* in_sizes, int n_in,
                              void* d_out, int out_size, void* d_ws, size_t ws_size,
                              hipStream_t stream) {
    const float* vectors     = (const float*)d_in[0];
    const float* node_feats  = (const float*)d_in[1];
    const int*   node_specie = (const int*)d_in[2];
    const float* radial      = (const float*)d_in[3];
    const int*   senders     = (const int*)d_in[4];
    const int*   receivers   = (const int*)d_in[5];
    const float* W_up_s      = (const float*)d_in[6];
    const float* W_up_v      = (const float*)d_in[7];
    const float* mlp_w1      = (const float*)d_in[8];
    const float* mlp_w2      = (const float*)d_in[9];
    const float* mlp_w3      = (const float*)d_in[10];
    const float* mlp_wo      = (const float*)d_in[11];
    const float* W_skip_s    = (const float*)d_in[12];
    const float* W_skip_v    = (const float*)d_in[13];
    const float* W_down_s    = (const float*)d_in[14];
    const float* W_down_v    = (const float*)d_in[15];
    float* out = (float*)d_out;

    float* up  = (float*)d_ws;                  // N*256 floats = 20.48 MB
    float* agg = up + (size_t)NN * 256;         // N*512 floats = 40.96 MB

    hipMemsetAsync(agg, 0, (size_t)NN * 512 * sizeof(float), stream);
    up_kernel<<<(NN + 3) / 4, 256, 0, stream>>>(node_feats, W_up_s, W_up_v, up);
    edge_kernel<<<(EE + 255) / 256, 256, 0, stream>>>(
        vectors, radial, senders, receivers,
        mlp_w1, mlp_w2, mlp_w3, mlp_wo, up, agg);
    node_kernel<<<(NN + 3) / 4, 256, 0, stream>>>(
        node_feats, node_specie, W_down_s, W_down_v, W_skip_s, W_skip_v, agg, out);
}

// Round 3
// 1281.930 us; speedup vs baseline: 6.9649x; 1.5759x over previous
//
#include <hip/hip_runtime.h>
#include <hip/hip_fp16.h>

#define NN 20000
#define EE 320000

__device__ __forceinline__ float silu_f(float x) {
    return x / (1.0f + __expf(-x));
}

// ---------------- Kernel 1: node up-projection (16 nodes/block) ----------------
__global__ __launch_bounds__(256) void up_kernel(
    const float* __restrict__ nf, const float* __restrict__ Wus,
    const float* __restrict__ Wuv, float* __restrict__ up)
{
    __shared__ float sWs[64 * 64];
    __shared__ float sWv[64 * 64];
    int tid = threadIdx.x;
    for (int i = tid; i < 64 * 64; i += 256) { sWs[i] = Wus[i]; sWv[i] = Wuv[i]; }
    __syncthreads();
    int lane = tid & 63, wv = tid >> 6;
    for (int it = 0; it < 4; it++) {
        int n = blockIdx.x * 16 + wv * 4 + it;          // 1250*16 = 20000 exact
        const float* row = nf + (size_t)n * 256;
        float s  = row[lane];
        float v0 = row[64 + lane * 3 + 0];
        float v1 = row[64 + lane * 3 + 1];
        float v2 = row[64 + lane * 3 + 2];
        float as = 0.f, a0 = 0.f, a1 = 0.f, a2 = 0.f;
        #pragma unroll 8
        for (int m = 0; m < 64; m++) {
            float sm = __shfl(s, m);
            float b0 = __shfl(v0, m), b1 = __shfl(v1, m), b2 = __shfl(v2, m);
            float w_s = sWs[m * 64 + lane];
            float w_v = sWv[m * 64 + lane];
            as += sm * w_s;
            a0 += b0 * w_v; a1 += b1 * w_v; a2 += b2 * w_v;
        }
        float* o = up + (size_t)n * 256;
        o[lane] = as * 0.125f;
        o[64 + lane * 3 + 0] = a0 * 0.125f;
        o[64 + lane * 3 + 1] = a1 * 0.125f;
        o[64 + lane * 3 + 2] = a2 * 0.125f;
    }
}

// ---------------- Kernel 2: fused edge MLP + wave-coalesced atomic scatter ----------------
// LDS ~53 KiB -> 3 blocks/CU (12 waves/CU). Hidden activations fp16x2-packed,
// single in-place buffer (thread-private columns, no barriers). Output in 16
// chunks of 16 features through a 16 KiB XOR-swizzled transpose buffer; scatter
// does 4 edges x 16 features per atomic wave-instruction (contiguous 64B spans).
__global__ __launch_bounds__(256) void edge_kernel(
    const float* __restrict__ vectors, const float* __restrict__ radial,
    const int* __restrict__ senders, const int* __restrict__ receivers,
    const float* __restrict__ w1, const float* __restrict__ w2,
    const float* __restrict__ w3, const float* __restrict__ wo,
    const float* __restrict__ up, float* __restrict__ agg)
{
    __shared__ __half2 hL[32 * 256];   // 32 KiB: hidden (fp16 pairs), per-thread column
    __shared__ float   T[16 * 256];    // 16 KiB: transpose buffer for one 16-feature chunk
    __shared__ float   sVec[256 * 3];  // 3 KiB
    __shared__ int     sSnd[256];      // 1 KiB
    __shared__ int     sRcv[256];      // 1 KiB   total ~53 KiB

    int tid = threadIdx.x;
    int e = blockIdx.x * 256 + tid;    // 1250*256 = 320000 exact, no tail
    int snd = senders[e];
    int rcv = receivers[e];
    float4 ra = *(const float4*)(radial + (size_t)e * 8);
    float4 rb = *(const float4*)(radial + (size_t)e * 8 + 4);
    float vx = vectors[(size_t)e * 3 + 0];
    float vy = vectors[(size_t)e * 3 + 1];
    float vz = vectors[(size_t)e * 3 + 2];
    sSnd[tid] = snd;
    sRcv[tid] = rcv;
    sVec[tid * 3 + 0] = vx;
    sVec[tid * 3 + 1] = vy;
    sVec[tid * 3 + 2] = vz;
    float len2 = vx * vx + vy * vy + vz * vz;
    float mask = (len2 > 0.f) ? 1.f : 0.f;

    // ---- layer 1: 8 -> 64 (fully unrolled, weights wave-uniform) ----
    {
        float a[64];
        #pragma unroll
        for (int j = 0; j < 64; j++) {
            float acc = ra.x * w1[j]       + ra.y * w1[64 + j]
                      + ra.z * w1[128 + j] + ra.w * w1[192 + j]
                      + rb.x * w1[256 + j] + rb.y * w1[320 + j]
                      + rb.z * w1[384 + j] + rb.w * w1[448 + j];
            a[j] = silu_f(acc * 0.35355339059327373f);
        }
        #pragma unroll
        for (int jp = 0; jp < 32; jp++)
            hL[jp * 256 + tid] = __floats2half2_rn(a[2 * jp], a[2 * jp + 1]);
    }
    // ---- layer 2: 64 -> 64 (in-place, per-thread column) ----
    {
        float acc[64];
        #pragma unroll
        for (int j = 0; j < 64; j++) acc[j] = 0.f;
        #pragma unroll 2
        for (int kp = 0; kp < 32; kp++) {
            float2 hf = __half22float2(hL[kp * 256 + tid]);
            const float* wr0 = w2 + (size_t)(2 * kp) * 64;
            const float* wr1 = w2 + (size_t)(2 * kp + 1) * 64;
            #pragma unroll
            for (int j = 0; j < 64; j++) acc[j] += hf.x * wr0[j] + hf.y * wr1[j];
        }
        #pragma unroll
        for (int jp = 0; jp < 32; jp++)
            hL[jp * 256 + tid] = __floats2half2_rn(silu_f(acc[2 * jp] * 0.125f),
                                                   silu_f(acc[2 * jp + 1] * 0.125f));
    }
    // ---- layer 3: 64 -> 64 ----
    {
        float acc[64];
        #pragma unroll
        for (int j = 0; j < 64; j++) acc[j] = 0.f;
        #pragma unroll 2
        for (int kp = 0; kp < 32; kp++) {
            float2 hf = __half22float2(hL[kp * 256 + tid]);
            const float* wr0 = w3 + (size_t)(2 * kp) * 64;
            const float* wr1 = w3 + (size_t)(2 * kp + 1) * 64;
            #pragma unroll
            for (int j = 0; j < 64; j++) acc[j] += hf.x * wr0[j] + hf.y * wr1[j];
        }
        #pragma unroll
        for (int jp = 0; jp < 32; jp++)
            hL[jp * 256 + tid] = __floats2half2_rn(silu_f(acc[2 * jp] * 0.125f),
                                                   silu_f(acc[2 * jp + 1] * 0.125f));
    }

    int lane  = tid & 63;
    int wbase = tid & 192;      // wave's first column
    int f = lane & 15;          // feature within chunk
    int g = lane >> 4;          // edge sub-index (4 edges per instr)

    // chunk compute: ao[16] = mix[e][c*16 .. c*16+15]
    #define COMPUTE_CHUNK(c, ao)                                                \
        {                                                                       \
            _Pragma("unroll")                                                   \
            for (int j = 0; j < 16; j++) ao[j] = 0.f;                           \
            _Pragma("unroll 4")                                                 \
            for (int kp = 0; kp < 32; kp++) {                                   \
                float2 hf = __half22float2(hL[kp * 256 + tid]);                 \
                const float* wr0 = wo + (size_t)(2 * kp) * 256 + (c) * 16;      \
                const float* wr1 = wo + (size_t)(2 * kp + 1) * 256 + (c) * 16;  \
                _Pragma("unroll")                                               \
                for (int j = 0; j < 16; j++)                                    \
                    ao[j] += hf.x * wr0[j] + hf.y * wr1[j];                     \
            }                                                                   \
            _Pragma("unroll")                                                   \
            for (int j = 0; j < 16; j++) ao[j] *= 0.125f * mask;                \
        }

    #define WRITE_T(ao)                                                         \
        __syncthreads();                                                        \
        _Pragma("unroll")                                                       \
        for (int j = 0; j < 16; j++) T[j * 256 + (tid ^ (2 * j))] = ao[j];      \
        __syncthreads();

    // ---- section A: features 0..63  (msg_s = es * mix) ----
    for (int c = 0; c < 4; c++) {
        float ao[16];
        COMPUTE_CHUNK(c, ao)
        WRITE_T(ao)
        for (int el = 0; el < 16; el++) {
            int col = wbase + el * 4 + g;
            int s_ = sSnd[col], rc = sRcv[col];
            float mx = T[f * 256 + (col ^ (2 * f))];
            int jf = c * 16 + f;
            atomicAdd(agg + (size_t)rc * 512 + jf, up[(size_t)s_ * 256 + jf] * mx);
        }
    }
    // ---- section B: features 64..127  (tp_s = (ev . vec)/len * mix) ----
    for (int c = 4; c < 8; c++) {
        float ao[16];
        COMPUTE_CHUNK(c, ao)
        WRITE_T(ao)
        for (int el = 0; el < 16; el++) {
            int col = wbase + el * 4 + g;
            int s_ = sSnd[col], rc = sRcv[col];
            float wx = sVec[col * 3 + 0], wy = sVec[col * 3 + 1], wz = sVec[col * 3 + 2];
            float l2 = wx * wx + wy * wy + wz * wz;
            float il = (l2 > 0.f) ? rsqrtf(l2) : 0.f;
            float mx = T[f * 256 + (col ^ (2 * f))];
            int m = (c - 4) * 16 + f;
            const float* ev = up + (size_t)s_ * 256 + 64 + m * 3;
            float dot = ev[0] * wx + ev[1] * wy + ev[2] * wz;
            atomicAdd(agg + (size_t)rc * 512 + 64 + m, dot * il * mx);
        }
    }
    // ---- section C: features 128..191  (msg_v = ev * mix), d-major agg layout ----
    for (int c = 8; c < 12; c++) {
        float ao[16];
        COMPUTE_CHUNK(c, ao)
        WRITE_T(ao)
        for (int el = 0; el < 16; el++) {
            int col = wbase + el * 4 + g;
            int s_ = sSnd[col], rc = sRcv[col];
            float mx = T[f * 256 + (col ^ (2 * f))];
            int m = (c - 8) * 16 + f;
            const float* ev = up + (size_t)s_ * 256 + 64 + m * 3;
            float* ag = agg + (size_t)rc * 512 + 128 + m;
            atomicAdd(ag + 0,   ev[0] * mx);
            atomicAdd(ag + 64,  ev[1] * mx);
            atomicAdd(ag + 128, ev[2] * mx);
        }
    }
    // ---- section D: features 192..255  (msg_v = es * y * mix), d-major ----
    for (int c = 12; c < 16; c++) {
        float ao[16];
        COMPUTE_CHUNK(c, ao)
        WRITE_T(ao)
        for (int el = 0; el < 16; el++) {
            int col = wbase + el * 4 + g;
            int s_ = sSnd[col], rc = sRcv[col];
            float wx = sVec[col * 3 + 0], wy = sVec[col * 3 + 1], wz = sVec[col * 3 + 2];
            float l2 = wx * wx + wy * wy + wz * wz;
            float il = (l2 > 0.f) ? rsqrtf(l2) : 0.f;
            float mx = T[f * 256 + (col ^ (2 * f))];
            int m = (c - 12) * 16 + f;
            float sc = up[(size_t)s_ * 256 + m] * 1.7320508075688772f * il * mx;
            float* ag = agg + (size_t)rc * 512 + 320 + m;
            atomicAdd(ag + 0,   sc * wx);
            atomicAdd(ag + 64,  sc * wy);
            atomicAdd(ag + 128, sc * wz);
        }
    }
    #undef COMPUTE_CHUNK
    #undef WRITE_T
}

// ---------------- Kernel 3: node tail (down + skip + gate + relu), 16 nodes/block ----------------
__global__ __launch_bounds__(256) void node_kernel(
    const float* __restrict__ nf, const int* __restrict__ specie,
    const float* __restrict__ Wds, const float* __restrict__ Wdv,
    const float* __restrict__ Wss, const float* __restrict__ Wsv,
    const float* __restrict__ agg, float* __restrict__ out)
{
    __shared__ float sDs[128 * 128];  // 64 KiB
    __shared__ float sDv[128 * 64];   // 32 KiB
    int tid = threadIdx.x;
    for (int i = tid; i < 128 * 128; i += 256) sDs[i] = Wds[i];
    for (int i = tid; i < 128 * 64; i += 256) sDv[i] = Wdv[i];
    __syncthreads();
    int lane = tid & 63, wv = tid >> 6;
    for (int it = 0; it < 4; it++) {
        int n = blockIdx.x * 16 + wv * 4 + it;
        const float* arow = agg + (size_t)n * 512;
        const float inv_nei = 0.25f;  // 1/sqrt(16)
        float as0 = arow[lane] * inv_nei;
        float as1 = arow[64 + lane] * inv_nei;
        float av00 = arow[128 + 0 * 64 + lane] * inv_nei;   // d-major layout
        float av01 = arow[128 + 1 * 64 + lane] * inv_nei;
        float av02 = arow[128 + 2 * 64 + lane] * inv_nei;
        float av10 = arow[320 + 0 * 64 + lane] * inv_nei;
        float av11 = arow[320 + 1 * 64 + lane] * inv_nei;
        float av12 = arow[320 + 2 * 64 + lane] * inv_nei;
        const float* row = nf + (size_t)n * 256;
        float s   = row[lane];
        float vv0 = row[64 + lane * 3 + 0];
        float vv1 = row[64 + lane * 3 + 1];
        float vv2 = row[64 + lane * 3 + 2];

        float f0 = 0.f, f1 = 0.f, fv0 = 0.f, fv1 = 0.f, fv2 = 0.f;
        #pragma unroll 8
        for (int m = 0; m < 64; m++) {
            float am = __shfl(as0, m);
            f0 += am * sDs[m * 128 + lane];
            f1 += am * sDs[m * 128 + 64 + lane];
            float b0 = __shfl(av00, m), b1 = __shfl(av01, m), b2 = __shfl(av02, m);
            float wd = sDv[m * 64 + lane];
            fv0 += b0 * wd; fv1 += b1 * wd; fv2 += b2 * wd;
        }
        #pragma unroll 8
        for (int m = 0; m < 64; m++) {
            float am = __shfl(as1, m);
            f0 += am * sDs[(64 + m) * 128 + lane];
            f1 += am * sDs[(64 + m) * 128 + 64 + lane];
            float b0 = __shfl(av10, m), b1 = __shfl(av11, m), b2 = __shfl(av12, m);
            float wd = sDv[(64 + m) * 64 + lane];
            fv0 += b0 * wd; fv1 += b1 * wd; fv2 += b2 * wd;
        }
        const float inv2m = 0.08838834764831845f;  // 1/sqrt(128)
        f0 *= inv2m; f1 *= inv2m; fv0 *= inv2m; fv1 *= inv2m; fv2 *= inv2m;

        int sp = specie[n];
        const float* Ws = Wss + (size_t)sp * 64 * 128;
        const float* Wv = Wsv + (size_t)sp * 64 * 64;
        float g0 = 0.f, g1 = 0.f, h0 = 0.f, h1 = 0.f, h2 = 0.f;
        #pragma unroll 4
        for (int m = 0; m < 64; m++) {
            float sm = __shfl(s, m);
            g0 += sm * Ws[m * 128 + lane];
            g1 += sm * Ws[m * 128 + 64 + lane];
            float b0 = __shfl(vv0, m), b1 = __shfl(vv1, m), b2 = __shfl(vv2, m);
            float wsk = Wv[m * 64 + lane];
            h0 += b0 * wsk; h1 += b1 * wsk; h2 += b2 * wsk;
        }
        f0 += g0 * 0.125f; f1 += g1 * 0.125f;
        fv0 += h0 * 0.125f; fv1 += h1 * 0.125f; fv2 += h2 * 0.125f;

        float gs   = silu_f(f0);
        float gate = silu_f(f1);
        float* orow = out + (size_t)n * 256;
        orow[lane] = fmaxf(gs, 0.f);
        orow[64 + lane * 3 + 0] = fmaxf(gate * fv0, 0.f);
        orow[64 + lane * 3 + 1] = fmaxf(gate * fv1, 0.f);
        orow[64 + lane * 3 + 2] = fmaxf(gate * fv2, 0.f);
    }
}

extern "C" void kernel_launch(void* const* d_in, const int* in_sizes, int n_in,
                              void* d_out, int out_size, void* d_ws, size_t ws_size,
                              hipStream_t stream) {
    const float* vectors     = (const float*)d_in[0];
    const float* node_feats  = (const float*)d_in[1];
    const int*   node_specie = (const int*)d_in[2];
    const float* radial      = (const float*)d_in[3];
    const int*   senders     = (const int*)d_in[4];
    const int*   receivers   = (const int*)d_in[5];
    const float* W_up_s      = (const float*)d_in[6];
    const float* W_up_v      = (const float*)d_in[7];
    const float* mlp_w1      = (const float*)d_in[8];
    const float* mlp_w2      = (const float*)d_in[9];
    const float* mlp_w3      = (const float*)d_in[10];
    const float* mlp_wo      = (const float*)d_in[11];
    const float* W_skip_s    = (const float*)d_in[12];
    const float* W_skip_v    = (const float*)d_in[13];
    const float* W_down_s    = (const float*)d_in[14];
    const float* W_down_v    = (const float*)d_in[15];
    float* out = (float*)d_out;

    float* up  = (float*)d_ws;                  // N*256 floats = 20.48 MB
    float* agg = up + (size_t)NN * 256;         // N*512 floats = 40.96 MB

    hipMemsetAsync(agg, 0, (size_t)NN * 512 * sizeof(float), stream);
    up_kernel<<<1250, 256, 0, stream>>>(node_feats, W_up_s, W_up_v, up);
    edge_kernel<<<1250, 256, 0, stream>>>(
        vectors, radial, senders, receivers,
        mlp_w1, mlp_w2, mlp_w3, mlp_wo, up, agg);
    node_kernel<<<1250, 256, 0, stream>>>(
        node_feats, node_specie, W_down_s, W_down_v, W_skip_s, W_skip_v, agg, out);
}

// Round 6
// 1196.232 us; speedup vs baseline: 7.4639x; 1.0716x over previous
//
#include <hip/hip_runtime.h>
#include <hip/hip_fp16.h>

#define NN 20000
#define EE 320000

__device__ __forceinline__ float silu_f(float x) {
    return x / (1.0f + __expf(-x));
}

__device__ __forceinline__ unsigned pk_h2(float a, float b) {
    __half2 h = __floats2half2_rn(a, b);
    return *reinterpret_cast<unsigned*>(&h);
}

// ---------------- Kernel 1: node up-projection (16 nodes/block) ----------------
// dmajor=1: up2[n] = [ s(0..63) | evx(64..127) | evy(128..191) | evz(192..255) ]
// dmajor=0: legacy interleaved [ s(0..63) | ev[m][d] at 64+3m+d ]  (fallback path)
__global__ __launch_bounds__(256) void up_kernel(
    const float* __restrict__ nf, const float* __restrict__ Wus,
    const float* __restrict__ Wuv, float* __restrict__ up, int dmajor)
{
    __shared__ float sWs[64 * 64];
    __shared__ float sWv[64 * 64];
    int tid = threadIdx.x;
    for (int i = tid; i < 64 * 64; i += 256) { sWs[i] = Wus[i]; sWv[i] = Wuv[i]; }
    __syncthreads();
    int lane = tid & 63, wv = tid >> 6;
    for (int it = 0; it < 4; it++) {
        int n = blockIdx.x * 16 + wv * 4 + it;          // 1250*16 = 20000 exact
        const float* row = nf + (size_t)n * 256;
        float s  = row[lane];
        float v0 = row[64 + lane * 3 + 0];
        float v1 = row[64 + lane * 3 + 1];
        float v2 = row[64 + lane * 3 + 2];
        float as = 0.f, a0 = 0.f, a1 = 0.f, a2 = 0.f;
        #pragma unroll 8
        for (int m = 0; m < 64; m++) {
            float sm = __shfl(s, m);
            float b0 = __shfl(v0, m), b1 = __shfl(v1, m), b2 = __shfl(v2, m);
            float w_s = sWs[m * 64 + lane];
            float w_v = sWv[m * 64 + lane];
            as += sm * w_s;
            a0 += b0 * w_v; a1 += b1 * w_v; a2 += b2 * w_v;
        }
        float* o = up + (size_t)n * 256;
        if (dmajor) {
            o[lane]       = as * 0.125f;
            o[64  + lane] = a0 * 0.125f;
            o[128 + lane] = a1 * 0.125f;
            o[192 + lane] = a2 * 0.125f;
        } else {
            o[lane] = as * 0.125f;
            o[64 + lane * 3 + 0] = a0 * 0.125f;
            o[64 + lane * 3 + 1] = a1 * 0.125f;
            o[64 + lane * 3 + 2] = a2 * 0.125f;
        }
    }
}

// ---------------- Kernel 2: edge MLP -> mix (fp16, EDGE order, no CSR) ----------------
// Thread-per-edge; fp16 hidden in thread-private LDS columns; zero barriers.
// Each thread stores its 16-feature chunk as 2x uint4 (32B contiguous).
// LDS = 32 KiB -> 4 blocks/CU (16 waves/CU).
__global__ __launch_bounds__(256) void mlp_kernel(
    const float* __restrict__ radial,
    const float* __restrict__ w1, const float* __restrict__ w2,
    const float* __restrict__ w3, const float* __restrict__ wo,
    __half* __restrict__ mix)
{
    __shared__ __half2 hL[32 * 256];   // 32 KiB, thread-private columns

    int tid = threadIdx.x;
    int e = blockIdx.x * 256 + tid;    // 1250*256 = EE exact
    float4 ra = *(const float4*)(radial + (size_t)e * 8);
    float4 rb = *(const float4*)(radial + (size_t)e * 8 + 4);

    // layer 1: 8 -> 64
    {
        float a[64];
        #pragma unroll
        for (int j = 0; j < 64; j++) {
            float acc = ra.x * w1[j]       + ra.y * w1[64 + j]
                      + ra.z * w1[128 + j] + ra.w * w1[192 + j]
                      + rb.x * w1[256 + j] + rb.y * w1[320 + j]
                      + rb.z * w1[384 + j] + rb.w * w1[448 + j];
            a[j] = silu_f(acc * 0.35355339059327373f);
        }
        #pragma unroll
        for (int jp = 0; jp < 32; jp++)
            hL[jp * 256 + tid] = __floats2half2_rn(a[2 * jp], a[2 * jp + 1]);
    }
    // layer 2: 64 -> 64
    {
        float acc[64];
        #pragma unroll
        for (int j = 0; j < 64; j++) acc[j] = 0.f;
        #pragma unroll 2
        for (int kp = 0; kp < 32; kp++) {
            float2 hf = __half22float2(hL[kp * 256 + tid]);
            const float* wr0 = w2 + (size_t)(2 * kp) * 64;
            const float* wr1 = w2 + (size_t)(2 * kp + 1) * 64;
            #pragma unroll
            for (int j = 0; j < 64; j++) acc[j] += hf.x * wr0[j] + hf.y * wr1[j];
        }
        #pragma unroll
        for (int jp = 0; jp < 32; jp++)
            hL[jp * 256 + tid] = __floats2half2_rn(silu_f(acc[2 * jp] * 0.125f),
                                                   silu_f(acc[2 * jp + 1] * 0.125f));
    }
    // layer 3: 64 -> 64
    {
        float acc[64];
        #pragma unroll
        for (int j = 0; j < 64; j++) acc[j] = 0.f;
        #pragma unroll 2
        for (int kp = 0; kp < 32; kp++) {
            float2 hf = __half22float2(hL[kp * 256 + tid]);
            const float* wr0 = w3 + (size_t)(2 * kp) * 64;
            const float* wr1 = w3 + (size_t)(2 * kp + 1) * 64;
            #pragma unroll
            for (int j = 0; j < 64; j++) acc[j] += hf.x * wr0[j] + hf.y * wr1[j];
        }
        #pragma unroll
        for (int jp = 0; jp < 32; jp++)
            hL[jp * 256 + tid] = __floats2half2_rn(silu_f(acc[2 * jp] * 0.125f),
                                                   silu_f(acc[2 * jp + 1] * 0.125f));
    }

    // output layer: 64 -> 256 in 16 chunks of 16; direct packed stores
    for (int c = 0; c < 16; c++) {
        float ao[16];
        #pragma unroll
        for (int j = 0; j < 16; j++) ao[j] = 0.f;
        #pragma unroll 4
        for (int kp = 0; kp < 32; kp++) {
            float2 hf = __half22float2(hL[kp * 256 + tid]);
            const float* wr0 = wo + (size_t)(2 * kp) * 256 + c * 16;
            const float* wr1 = wo + (size_t)(2 * kp + 1) * 256 + c * 16;
            #pragma unroll
            for (int j = 0; j < 16; j++)
                ao[j] += hf.x * wr0[j] + hf.y * wr1[j];
        }
        #pragma unroll
        for (int j = 0; j < 16; j++) ao[j] *= 0.125f;
        uint4* dst = reinterpret_cast<uint4*>(mix + (size_t)e * 256 + c * 16);
        dst[0] = make_uint4(pk_h2(ao[0], ao[1]),  pk_h2(ao[2], ao[3]),
                            pk_h2(ao[4], ao[5]),  pk_h2(ao[6], ao[7]));
        dst[1] = make_uint4(pk_h2(ao[8], ao[9]),  pk_h2(ao[10], ao[11]),
                            pk_h2(ao[12], ao[13]), pk_h2(ao[14], ao[15]));
    }
}

// ---------------- Kernel 3: wave-per-edge atomic scatter (no LDS, no barriers) ----------------
// Per edge: 4 coalesced 128B mix loads + 4 coalesced up-row loads + 8 atomic
// wave-instructions, each a contiguous 256B span of the receiver's agg row.
__global__ __launch_bounds__(256) void scatter_kernel(
    const int* __restrict__ senders, const int* __restrict__ receivers,
    const float* __restrict__ vectors, const __half* __restrict__ mix,
    const float* __restrict__ up2, float* __restrict__ agg)
{
    int lane = threadIdx.x & 63;
    int wid  = (blockIdx.x * 256 + threadIdx.x) >> 6;   // global wave id
    int nw   = gridDim.x * 4;
    const float SQ3 = 1.7320508075688772f;

    for (int e = wid; e < EE; e += nw) {
        int snd = senders[e];
        int rcv = receivers[e];
        if ((unsigned)snd >= (unsigned)NN) snd = 0;
        if ((unsigned)rcv >= (unsigned)NN) rcv = 0;
        float vx = vectors[(size_t)e * 3 + 0];
        float vy = vectors[(size_t)e * 3 + 1];
        float vz = vectors[(size_t)e * 3 + 2];
        float l2 = vx * vx + vy * vy + vz * vz;
        float il   = (l2 > 0.f) ? rsqrtf(l2) : 0.f;
        float mask = (l2 > 0.f) ? 1.f : 0.f;

        const __half* mr = mix + (size_t)e * 256;
        float mA = __half2float(mr[lane])        * mask;
        float mB = __half2float(mr[64  + lane])  * mask;
        float mC = __half2float(mr[128 + lane])  * mask;
        float mD = __half2float(mr[192 + lane])  * mask;

        const float* u = up2 + (size_t)snd * 256;
        float s  = u[lane];
        float ex = u[64 + lane], ey = u[128 + lane], ez = u[192 + lane];

        float* ar = agg + (size_t)rcv * 512;
        atomicAdd(ar + lane,        s * mA);
        float tps = (ex * vx + ey * vy + ez * vz) * il;
        atomicAdd(ar + 64  + lane,  tps * mB);
        atomicAdd(ar + 128 + lane,  ex * mC);
        atomicAdd(ar + 192 + lane,  ey * mC);
        atomicAdd(ar + 256 + lane,  ez * mC);
        float yx = SQ3 * vx * il, yy = SQ3 * vy * il, yz = SQ3 * vz * il;
        float sD = s * mD;
        atomicAdd(ar + 320 + lane,  sD * yx);
        atomicAdd(ar + 384 + lane,  sD * yy);
        atomicAdd(ar + 448 + lane,  sD * yz);
    }
}

// ---------------- Kernel 4: node tail (down + skip + gate + relu) ----------------
__global__ __launch_bounds__(256) void node_kernel(
    const float* __restrict__ nf, const int* __restrict__ specie,
    const float* __restrict__ Wds, const float* __restrict__ Wdv,
    const float* __restrict__ Wss, const float* __restrict__ Wsv,
    const float* __restrict__ agg, float* __restrict__ out)
{
    __shared__ float sDs[128 * 128];  // 64 KiB
    __shared__ float sDv[128 * 64];   // 32 KiB
    int tid = threadIdx.x;
    for (int i = tid; i < 128 * 128; i += 256) sDs[i] = Wds[i];
    for (int i = tid; i < 128 * 64; i += 256) sDv[i] = Wdv[i];
    __syncthreads();
    int lane = tid & 63, wv = tid >> 6;
    for (int it = 0; it < 4; it++) {
        int n = blockIdx.x * 16 + wv * 4 + it;
        const float* arow = agg + (size_t)n * 512;
        const float inv_nei = 0.25f;
        float as0 = arow[lane] * inv_nei;
        float as1 = arow[64 + lane] * inv_nei;
        float av00 = arow[128 + lane] * inv_nei;
        float av01 = arow[192 + lane] * inv_nei;
        float av02 = arow[256 + lane] * inv_nei;
        float av10 = arow[320 + lane] * inv_nei;
        float av11 = arow[384 + lane] * inv_nei;
        float av12 = arow[448 + lane] * inv_nei;
        const float* row = nf + (size_t)n * 256;
        float s   = row[lane];
        float vv0 = row[64 + lane * 3 + 0];
        float vv1 = row[64 + lane * 3 + 1];
        float vv2 = row[64 + lane * 3 + 2];

        float f0 = 0.f, f1 = 0.f, fv0 = 0.f, fv1 = 0.f, fv2 = 0.f;
        #pragma unroll 8
        for (int m = 0; m < 64; m++) {
            float am = __shfl(as0, m);
            f0 += am * sDs[m * 128 + lane];
            f1 += am * sDs[m * 128 + 64 + lane];
            float b0 = __shfl(av00, m), b1 = __shfl(av01, m), b2 = __shfl(av02, m);
            float wd = sDv[m * 64 + lane];
            fv0 += b0 * wd; fv1 += b1 * wd; fv2 += b2 * wd;
        }
        #pragma unroll 8
        for (int m = 0; m < 64; m++) {
            float am = __shfl(as1, m);
            f0 += am * sDs[(64 + m) * 128 + lane];
            f1 += am * sDs[(64 + m) * 128 + 64 + lane];
            float b0 = __shfl(av10, m), b1 = __shfl(av11, m), b2 = __shfl(av12, m);
            float wd = sDv[(64 + m) * 64 + lane];
            fv0 += b0 * wd; fv1 += b1 * wd; fv2 += b2 * wd;
        }
        const float inv2m = 0.08838834764831845f;
        f0 *= inv2m; f1 *= inv2m; fv0 *= inv2m; fv1 *= inv2m; fv2 *= inv2m;

        int sp = specie[n];
        if ((unsigned)sp >= 5u) sp = 0;
        const float* Ws = Wss + (size_t)sp * 64 * 128;
        const float* Wv = Wsv + (size_t)sp * 64 * 64;
        float g0 = 0.f, g1 = 0.f, h0 = 0.f, h1 = 0.f, h2 = 0.f;
        #pragma unroll 4
        for (int m = 0; m < 64; m++) {
            float sm = __shfl(s, m);
            g0 += sm * Ws[m * 128 + lane];
            g1 += sm * Ws[m * 128 + 64 + lane];
            float b0 = __shfl(vv0, m), b1 = __shfl(vv1, m), b2 = __shfl(vv2, m);
            float wsk = Wv[m * 64 + lane];
            h0 += b0 * wsk; h1 += b1 * wsk; h2 += b2 * wsk;
        }
        f0 += g0 * 0.125f; f1 += g1 * 0.125f;
        fv0 += h0 * 0.125f; fv1 += h1 * 0.125f; fv2 += h2 * 0.125f;

        float gs   = silu_f(f0);
        float gate = silu_f(f1);
        float* orow = out + (size_t)n * 256;
        orow[lane] = fmaxf(gs, 0.f);
        orow[64 + lane * 3 + 0] = fmaxf(gate * fv0, 0.f);
        orow[64 + lane * 3 + 1] = fmaxf(gate * fv1, 0.f);
        orow[64 + lane * 3 + 2] = fmaxf(gate * fv2, 0.f);
    }
}

// ---------------- Fallback: round-3 fused edge kernel (interleaved up layout) ----------------
__global__ __launch_bounds__(256) void edge_kernel_fb(
    const float* __restrict__ vectors, const float* __restrict__ radial,
    const int* __restrict__ senders, const int* __restrict__ receivers,
    const float* __restrict__ w1, const float* __restrict__ w2,
    const float* __restrict__ w3, const float* __restrict__ wo,
    const float* __restrict__ up, float* __restrict__ agg)
{
    __shared__ __half2 hL[32 * 256];
    __shared__ float   T[16 * 256];
    __shared__ float   sVec[256 * 3];
    __shared__ int     sSnd[256];
    __shared__ int     sRcv[256];

    int tid = threadIdx.x;
    int e = blockIdx.x * 256 + tid;
    int snd = senders[e];
    int rcv = receivers[e];
    if ((unsigned)snd >= (unsigned)NN) snd = 0;
    if ((unsigned)rcv >= (unsigned)NN) rcv = 0;
    float4 ra = *(const float4*)(radial + (size_t)e * 8);
    float4 rb = *(const float4*)(radial + (size_t)e * 8 + 4);
    float vx = vectors[(size_t)e * 3 + 0];
    float vy = vectors[(size_t)e * 3 + 1];
    float vz = vectors[(size_t)e * 3 + 2];
    sSnd[tid] = snd; sRcv[tid] = rcv;
    sVec[tid * 3 + 0] = vx; sVec[tid * 3 + 1] = vy; sVec[tid * 3 + 2] = vz;
    float len2 = vx * vx + vy * vy + vz * vz;
    float mask = (len2 > 0.f) ? 1.f : 0.f;

    {
        float a[64];
        #pragma unroll
        for (int j = 0; j < 64; j++) {
            float acc = ra.x * w1[j]       + ra.y * w1[64 + j]
                      + ra.z * w1[128 + j] + ra.w * w1[192 + j]
                      + rb.x * w1[256 + j] + rb.y * w1[320 + j]
                      + rb.z * w1[384 + j] + rb.w * w1[448 + j];
            a[j] = silu_f(acc * 0.35355339059327373f);
        }
        #pragma unroll
        for (int jp = 0; jp < 32; jp++)
            hL[jp * 256 + tid] = __floats2half2_rn(a[2 * jp], a[2 * jp + 1]);
    }
    {
        float acc[64];
        #pragma unroll
        for (int j = 0; j < 64; j++) acc[j] = 0.f;
        #pragma unroll 2
        for (int kp = 0; kp < 32; kp++) {
            float2 hf = __half22float2(hL[kp * 256 + tid]);
            const float* wr0 = w2 + (size_t)(2 * kp) * 64;
            const float* wr1 = w2 + (size_t)(2 * kp + 1) * 64;
            #pragma unroll
            for (int j = 0; j < 64; j++) acc[j] += hf.x * wr0[j] + hf.y * wr1[j];
        }
        #pragma unroll
        for (int jp = 0; jp < 32; jp++)
            hL[jp * 256 + tid] = __floats2half2_rn(silu_f(acc[2 * jp] * 0.125f),
                                                   silu_f(acc[2 * jp + 1] * 0.125f));
    }
    {
        float acc[64];
        #pragma unroll
        for (int j = 0; j < 64; j++) acc[j] = 0.f;
        #pragma unroll 2
        for (int kp = 0; kp < 32; kp++) {
            float2 hf = __half22float2(hL[kp * 256 + tid]);
            const float* wr0 = w3 + (size_t)(2 * kp) * 64;
            const float* wr1 = w3 + (size_t)(2 * kp + 1) * 64;
            #pragma unroll
            for (int j = 0; j < 64; j++) acc[j] += hf.x * wr0[j] + hf.y * wr1[j];
        }
        #pragma unroll
        for (int jp = 0; jp < 32; jp++)
            hL[jp * 256 + tid] = __floats2half2_rn(silu_f(acc[2 * jp] * 0.125f),
                                                   silu_f(acc[2 * jp + 1] * 0.125f));
    }

    int lane  = tid & 63;
    int wbase = tid & 192;
    int f = lane & 15;
    int g = lane >> 4;

    #define COMPUTE_CHUNK(c, ao)                                                \
        {                                                                       \
            _Pragma("unroll")                                                   \
            for (int j = 0; j < 16; j++) ao[j] = 0.f;                           \
            _Pragma("unroll 4")                                                 \
            for (int kp = 0; kp < 32; kp++) {                                   \
                float2 hf = __half22float2(hL[kp * 256 + tid]);                 \
                const float* wr0 = wo + (size_t)(2 * kp) * 256 + (c) * 16;      \
                const float* wr1 = wo + (size_t)(2 * kp + 1) * 256 + (c) * 16;  \
                _Pragma("unroll")                                               \
                for (int j = 0; j < 16; j++)                                    \
                    ao[j] += hf.x * wr0[j] + hf.y * wr1[j];                     \
            }                                                                   \
            _Pragma("unroll")                                                   \
            for (int j = 0; j < 16; j++) ao[j] *= 0.125f * mask;                \
        }

    #define WRITE_T(ao)                                                         \
        __syncthreads();                                                        \
        _Pragma("unroll")                                                       \
        for (int j = 0; j < 16; j++) T[j * 256 + (tid ^ (2 * j))] = ao[j];      \
        __syncthreads();

    for (int c = 0; c < 4; c++) {
        float ao[16];
        COMPUTE_CHUNK(c, ao)
        WRITE_T(ao)
        for (int el = 0; el < 16; el++) {
            int col = wbase + el * 4 + g;
            int s_ = sSnd[col], rc = sRcv[col];
            float mx = T[f * 256 + (col ^ (2 * f))];
            int jf = c * 16 + f;
            atomicAdd(agg + (size_t)rc * 512 + jf, up[(size_t)s_ * 256 + jf] * mx);
        }
    }
    for (int c = 4; c < 8; c++) {
        float ao[16];
        COMPUTE_CHUNK(c, ao)
        WRITE_T(ao)
        for (int el = 0; el < 16; el++) {
            int col = wbase + el * 4 + g;
            int s_ = sSnd[col], rc = sRcv[col];
            float wx = sVec[col * 3 + 0], wy = sVec[col * 3 + 1], wz = sVec[col * 3 + 2];
            float l2 = wx * wx + wy * wy + wz * wz;
            float il = (l2 > 0.f) ? rsqrtf(l2) : 0.f;
            float mx = T[f * 256 + (col ^ (2 * f))];
            int m = (c - 4) * 16 + f;
            const float* ev = up + (size_t)s_ * 256 + 64 + m * 3;
            float dot = ev[0] * wx + ev[1] * wy + ev[2] * wz;
            atomicAdd(agg + (size_t)rc * 512 + 64 + m, dot * il * mx);
        }
    }
    for (int c = 8; c < 12; c++) {
        float ao[16];
        COMPUTE_CHUNK(c, ao)
        WRITE_T(ao)
        for (int el = 0; el < 16; el++) {
            int col = wbase + el * 4 + g;
            int s_ = sSnd[col], rc = sRcv[col];
            float mx = T[f * 256 + (col ^ (2 * f))];
            int m = (c - 8) * 16 + f;
            const float* ev = up + (size_t)s_ * 256 + 64 + m * 3;
            float* ag = agg + (size_t)rc * 512 + 128 + m;
            atomicAdd(ag + 0,   ev[0] * mx);
            atomicAdd(ag + 64,  ev[1] * mx);
            atomicAdd(ag + 128, ev[2] * mx);
        }
    }
    for (int c = 12; c < 16; c++) {
        float ao[16];
        COMPUTE_CHUNK(c, ao)
        WRITE_T(ao)
        for (int el = 0; el < 16; el++) {
            int col = wbase + el * 4 + g;
            int s_ = sSnd[col], rc = sRcv[col];
            float wx = sVec[col * 3 + 0], wy = sVec[col * 3 + 1], wz = sVec[col * 3 + 2];
            float l2 = wx * wx + wy * wy + wz * wz;
            float il = (l2 > 0.f) ? rsqrtf(l2) : 0.f;
            float mx = T[f * 256 + (col ^ (2 * f))];
            int m = (c - 12) * 16 + f;
            float sc = up[(size_t)s_ * 256 + m] * 1.7320508075688772f * il * mx;
            float* ag = agg + (size_t)rc * 512 + 320 + m;
            atomicAdd(ag + 0,   sc * wx);
            atomicAdd(ag + 64,  sc * wy);
            atomicAdd(ag + 128, sc * wz);
        }
    }
    #undef COMPUTE_CHUNK
    #undef WRITE_T
}

extern "C" void kernel_launch(void* const* d_in, const int* in_sizes, int n_in,
                              void* d_out, int out_size, void* d_ws, size_t ws_size,
                              hipStream_t stream) {
    const float* vectors     = (const float*)d_in[0];
    const float* node_feats  = (const float*)d_in[1];
    const int*   node_specie = (const int*)d_in[2];
    const float* radial      = (const float*)d_in[3];
    const int*   senders     = (const int*)d_in[4];
    const int*   receivers   = (const int*)d_in[5];
    const float* W_up_s      = (const float*)d_in[6];
    const float* W_up_v      = (const float*)d_in[7];
    const float* mlp_w1      = (const float*)d_in[8];
    const float* mlp_w2      = (const float*)d_in[9];
    const float* mlp_w3      = (const float*)d_in[10];
    const float* mlp_wo      = (const float*)d_in[11];
    const float* W_skip_s    = (const float*)d_in[12];
    const float* W_skip_v    = (const float*)d_in[13];
    const float* W_down_s    = (const float*)d_in[14];
    const float* W_down_v    = (const float*)d_in[15];
    float* out = (float*)d_out;

    // workspace layout: up | agg | mix (256B-aligned)
    float* up  = (float*)d_ws;                       // NN*256 f32  = 20.48 MB
    float* agg = up + (size_t)NN * 256;              // NN*512 f32  = 40.96 MB
    uintptr_t mix_addr = ((uintptr_t)(agg + (size_t)NN * 512) + 255) & ~(uintptr_t)255;
    __half* mix = (__half*)mix_addr;                 // EE*256 fp16 = 163.84 MB
    size_t required = (size_t)(mix_addr + (size_t)EE * 256 * sizeof(__half)
                               - (uintptr_t)d_ws);

    if (ws_size >= required) {
        // ---- materialized-mix (edge order) + high-occupancy atomic scatter ----
        hipMemsetAsync(agg, 0, (size_t)NN * 512 * sizeof(float), stream);
        up_kernel<<<NN / 16, 256, 0, stream>>>(node_feats, W_up_s, W_up_v, up, 1);
        mlp_kernel<<<EE / 256, 256, 0, stream>>>(radial,
            mlp_w1, mlp_w2, mlp_w3, mlp_wo, mix);
        scatter_kernel<<<2048, 256, 0, stream>>>(senders, receivers, vectors,
            mix, up, agg);
        node_kernel<<<NN / 16, 256, 0, stream>>>(node_feats, node_specie,
            W_down_s, W_down_v, W_skip_s, W_skip_v, agg, out);
    } else {
        // ---- fallback: round-3 fused atomic path ----
        hipMemsetAsync(agg, 0, (size_t)NN * 512 * sizeof(float), stream);
        up_kernel<<<NN / 16, 256, 0, stream>>>(node_feats, W_up_s, W_up_v, up, 0);
        edge_kernel_fb<<<EE / 256, 256, 0, stream>>>(
            vectors, radial, senders, receivers,
            mlp_w1, mlp_w2, mlp_w3, mlp_wo, up, agg);
        node_kernel<<<NN / 16, 256, 0, stream>>>(node_feats, node_specie,
            W_down_s, W_down_v, W_skip_s, W_skip_v, agg, out);
    }
}